// Round 1
// baseline (2873.947 us; speedup 1.0000x reference)
//
#include <hip/hip_runtime.h>
#include <hip/hip_bf16.h>
#include <math.h>

// ---------------- problem constants (from reference) ----------------
constexpr int N_ENT_C = 30000;
constexpr int N_REL_C = 500;
constexpr int D_IN_C  = 200;
constexpr int D_HID_C = 400;     // NHEADS * D_OUT1
constexpr int E1_C    = 250000;
constexpr int E2_C    = 50000;
constexpr int E_TOT_C = 300000;
constexpr int NB_C    = 8192;

static inline int ceil_div(int a, int b) { return (a + b - 1) / b; }

// ---------------- row-wise L2 normalize: out[n][:] = in[n][:]/max(||row||,1e-12)
__global__ void l2norm_rows(const float* __restrict__ in, float* __restrict__ out, int D) {
    int n = blockIdx.x;
    int lane = threadIdx.x; // 64
    const float* src = in + (size_t)n * D;
    float vals[7];
    float ss = 0.f;
#pragma unroll
    for (int i = 0; i < 7; ++i) {
        int o = lane + i * 64;
        float v = (o < D) ? src[o] : 0.f;
        vals[i] = v;
        ss += v * v;
    }
#pragma unroll
    for (int off = 32; off; off >>= 1) ss += __shfl_down(ss, off);
    ss = __shfl(ss, 0);
    float inv = 1.f / fmaxf(sqrtf(ss), 1e-12f);
    float* dst = out + (size_t)n * D;
#pragma unroll
    for (int i = 0; i < 7; ++i) {
        int o = lane + i * 64;
        if (o < D) dst[o] = vals[i] * inv;
    }
}

// ---------------- Wi = a_i + a_r ; Wj = a_j + a_r  (each 200x200, A is 200x600 row-major)
__global__ void combine_w(const float* __restrict__ A, float* __restrict__ Wi, float* __restrict__ Wj) {
    int i = blockIdx.x * 256 + threadIdx.x;
    if (i >= D_IN_C * D_IN_C) return;
    int o = i / D_IN_C, d = i % D_IN_C;
    float ar = A[o * 600 + 400 + d];
    Wi[i] = A[o * 600 + d] + ar;
    Wj[i] = A[o * 600 + 200 + d] + ar;
}

// ---------------- generic tiled f32 GEMM: C[M x N] = X[M x K(ldx)] * W
// NT: W indexed W[n*ldw + k] (optionally + W2[n*ldw + k]);  NN: W[k*ldw + n]
template <bool NT>
__global__ __launch_bounds__(256) void gemm_kernel(
    const float* __restrict__ X, int ldx,
    const float* __restrict__ W, const float* __restrict__ W2, int ldw,
    float* __restrict__ C, int ldc, int M, int N, int K)
{
    __shared__ float Xs[16][65];
    __shared__ float Ws[16][65];
    const int bm = blockIdx.y * 64;
    const int bn = blockIdx.x * 64;
    const int tid = threadIdx.x;
    const int tm = (tid >> 4) << 2;
    const int tn = (tid & 15) << 2;
    float acc[4][4] = {};
    for (int k0 = 0; k0 < K; k0 += 16) {
        for (int i = tid; i < 64 * 16; i += 256) {
            int mm = i >> 4, kk = i & 15;
            int m = bm + mm, k = k0 + kk;
            Xs[kk][mm] = (m < M && k < K) ? X[(size_t)m * ldx + k] : 0.f;
        }
        for (int i = tid; i < 64 * 16; i += 256) {
            int nn = i >> 4, kk = i & 15;
            int n = bn + nn, k = k0 + kk;
            float w = 0.f;
            if (n < N && k < K) {
                if (NT) {
                    w = W[(size_t)n * ldw + k];
                    if (W2) w += W2[(size_t)n * ldw + k];
                } else {
                    w = W[(size_t)k * ldw + n];
                }
            }
            Ws[kk][nn] = w;
        }
        __syncthreads();
#pragma unroll
        for (int kk = 0; kk < 16; ++kk) {
            float xv[4], wv[4];
#pragma unroll
            for (int a = 0; a < 4; ++a) xv[a] = Xs[kk][tm + a];
#pragma unroll
            for (int b = 0; b < 4; ++b) wv[b] = Ws[kk][tn + b];
#pragma unroll
            for (int a = 0; a < 4; ++a)
#pragma unroll
                for (int b = 0; b < 4; ++b) acc[a][b] += xv[a] * wv[b];
        }
        __syncthreads();
    }
#pragma unroll
    for (int a = 0; a < 4; ++a) {
        int m = bm + tm + a;
        if (m >= M) continue;
#pragma unroll
        for (int b = 0; b < 4; ++b) {
            int n = bn + tn + b;
            if (n < N) C[(size_t)m * ldc + n] = acc[a][b];
        }
    }
}

// ---------------- out[m] = sum_o A[m*lda+o] * v[o]
__global__ void rowdot(const float* __restrict__ A, int lda, const float* __restrict__ v,
                       float* __restrict__ out, int D) {
    int m = blockIdx.x;
    int lane = threadIdx.x; // 64
    const float* row = A + (size_t)m * lda;
    float s = 0.f;
    for (int o = lane; o < D; o += 64) s += row[o] * v[o];
#pragma unroll
    for (int off = 32; off; off >>= 1) s += __shfl_down(s, off);
    if (lane == 0) out[m] = s;
}

// ---------------- layer-1 edge scalar: logit -> edge_e, rowsum (per head)
__global__ void edge_scalar1(const int* __restrict__ el, const int* __restrict__ et,
                             const int* __restrict__ tin,
                             const float* __restrict__ si, const float* __restrict__ sj,
                             const float* __restrict__ sr,
                             float* __restrict__ ee, float* __restrict__ rowsum) {
    int k = blockIdx.x * 256 + threadIdx.x;
    if (k >= E_TOT_C) return;
    int e0;
    float dot;
    if (k < E1_C) {
        e0 = el[k];
        int e1 = el[E1_C + k];
        dot = si[e0] + sj[e1] + sr[et[k]];
    } else {
        const int4 t = ((const int4*)tin)[k - E1_C]; // (t0,t1,t2,t3)
        e0 = t.w;
        dot = si[t.w] + sj[t.x] + sr[t.y] + sr[t.z];
    }
    float p = (dot > 0.f) ? dot : 0.2f * dot; // leaky_relu
    float e = expf(-p);
    ee[k] = e;
    atomicAdd(rowsum + e0, e);
}

// ---------------- layer-1 payload scatter: out_ent[e0][hoff+o] += e * (Qj[e1][o] + R-terms[o])
__global__ __launch_bounds__(256) void scatter1(
    const int* __restrict__ el, const int* __restrict__ et, const int* __restrict__ tin,
    const float* __restrict__ edge_e, const float* __restrict__ Qj,
    const float* __restrict__ Rr, float* __restrict__ out_ent, int hoff) {
    int k = (blockIdx.x * 256 + threadIdx.x) >> 6; // wave per edge
    int lane = threadIdx.x & 63;
    if (k >= E_TOT_C) return;
    float e = edge_e[k];
    int e0, e1;
    const float* r0;
    const float* r1 = nullptr;
    if (k < E1_C) {
        e0 = el[k];
        e1 = el[E1_C + k];
        r0 = Rr + (size_t)et[k] * D_IN_C;
    } else {
        const int4 t = ((const int4*)tin)[k - E1_C];
        e0 = t.w;
        e1 = t.x;
        r0 = Rr + (size_t)t.y * D_IN_C;
        r1 = Rr + (size_t)t.z * D_IN_C;
    }
    const float* qj = Qj + (size_t)e1 * D_IN_C;
    float* dst = out_ent + (size_t)e0 * D_HID_C + hoff;
#pragma unroll
    for (int i = 0; i < 4; ++i) {
        int o = lane + i * 64;
        if (o < D_IN_C) {
            float v = qj[o] + r0[o];
            if (r1) v += r1[o];
            atomicAdd(dst + o, e * v);
        }
    }
}

// ---------------- layer-1 finalize (per head): h = elu(Qi + scatter/rowsum)
__global__ void fin1(float* __restrict__ out_ent, const float* __restrict__ Qi,
                     const float* __restrict__ rowsum, int hoff) {
    int n = blockIdx.x;
    int lane = threadIdx.x; // 64
    float rs = rowsum[n];
    float* dst = out_ent + (size_t)n * D_HID_C + hoff;
    const float* qi = Qi + (size_t)n * D_IN_C;
#pragma unroll
    for (int i = 0; i < 4; ++i) {
        int o = lane + i * 64;
        if (o < D_IN_C) {
            float v = (rs > 0.f) ? (qi[o] + dst[o] / rs) : 0.f;
            dst[o] = (v > 0.f) ? v : (expf(v) - 1.f); // elu
        }
    }
}

// ---------------- layer-2 edge scalar
__global__ void edge_scalar2(const int* __restrict__ el, const int* __restrict__ et,
                             const int* __restrict__ tin,
                             const float* __restrict__ ti, const float* __restrict__ tj,
                             const float* __restrict__ tr, const float* __restrict__ tv,
                             float* __restrict__ ee, float* __restrict__ rowsum,
                             float* __restrict__ rowsumNH) {
    int k = blockIdx.x * 256 + threadIdx.x;
    if (k >= E_TOT_C) return;
    int e0;
    float dot;
    bool nh = (k >= E1_C);
    if (!nh) {
        e0 = el[k];
        int e1 = el[E1_C + k];
        dot = ti[e0] + tj[e1] + tv[et[k]];
    } else {
        const int4 t = ((const int4*)tin)[k - E1_C];
        e0 = t.w;
        dot = ti[t.w] + tr[t.w] + tj[t.x] + tr[t.x] + tv[t.y] + tv[t.z];
    }
    float p = (dot > 0.f) ? dot : 0.2f * dot;
    float e = expf(-p);
    ee[k] = e;
    atomicAdd(rowsum + e0, e);
    if (nh) atomicAdd(rowsumNH + e0, e);
}

// ---------------- layer-2 payload scatter into h2 (= d_out)
__global__ __launch_bounds__(256) void scatter2(
    const int* __restrict__ el, const int* __restrict__ et, const int* __restrict__ tin,
    const float* __restrict__ edge_e, const float* __restrict__ Uj,
    const float* __restrict__ Ur, const float* __restrict__ Vr, float* __restrict__ h2) {
    int k = (blockIdx.x * 256 + threadIdx.x) >> 6;
    int lane = threadIdx.x & 63;
    if (k >= E_TOT_C) return;
    float e = edge_e[k];
    int e0, e1;
    const float* v0;
    const float* v1 = nullptr;
    bool nh = (k >= E1_C);
    if (!nh) {
        e0 = el[k];
        e1 = el[E1_C + k];
        v0 = Vr + (size_t)et[k] * D_HID_C;
    } else {
        const int4 t = ((const int4*)tin)[k - E1_C];
        e0 = t.w;
        e1 = t.x;
        v0 = Vr + (size_t)t.y * D_HID_C;
        v1 = Vr + (size_t)t.z * D_HID_C;
    }
    const float* uj = Uj + (size_t)e1 * D_HID_C;
    const float* ur = Ur + (size_t)e1 * D_HID_C;
    float* dst = h2 + (size_t)e0 * D_HID_C;
#pragma unroll
    for (int i = 0; i < 7; ++i) {
        int o = lane + i * 64;
        if (o < D_HID_C) {
            float v = uj[o] + v0[o];
            if (nh) v += ur[o] + v1[o];
            atomicAdd(dst + o, e * v);
        }
    }
}

// ---------------- mask scatter
__global__ void mask_scatter(const int* __restrict__ batch, float* __restrict__ mask) {
    int t = blockIdx.x * 256 + threadIdx.x;
    if (t >= NB_C) return;
    mask[batch[t * 3 + 2]] = 1.0f;
}

// ---------------- final out_ent: l2norm(Z + mask*elu(h2_full/rowsum)) written over d_out
__global__ void fin2(float* __restrict__ h2out, const float* __restrict__ Ui,
                     const float* __restrict__ Ur, const float* __restrict__ rs2,
                     const float* __restrict__ rsNH, const float* __restrict__ Z,
                     const float* __restrict__ mask) {
    int n = blockIdx.x;
    int lane = threadIdx.x; // 64
    float rs = rs2[n];
    float rnh = rsNH[n];
    float mk = mask[n];
    const float* ui = Ui + (size_t)n * D_HID_C;
    const float* ur = Ur + (size_t)n * D_HID_C;
    const float* z = Z + (size_t)n * D_HID_C;
    float* row = h2out + (size_t)n * D_HID_C;
    float vals[7];
    float ss = 0.f;
#pragma unroll
    for (int i = 0; i < 7; ++i) {
        int o = lane + i * 64;
        float v = 0.f;
        if (o < D_HID_C) {
            float hv = (rs > 0.f) ? (ui[o] + (row[o] + ur[o] * rnh) / rs) : 0.f;
            float oe = (hv > 0.f) ? hv : (expf(hv) - 1.f);
            v = z[o] + mk * oe;
        }
        vals[i] = v;
        ss += v * v;
    }
#pragma unroll
    for (int off = 32; off; off >>= 1) ss += __shfl_down(ss, off);
    ss = __shfl(ss, 0);
    float inv = 1.f / fmaxf(sqrtf(ss), 1e-12f);
#pragma unroll
    for (int i = 0; i < 7; ++i) {
        int o = lane + i * 64;
        if (o < D_HID_C) row[o] = vals[i] * inv;
    }
}

// =====================================================================
extern "C" void kernel_launch(void* const* d_in, const int* in_sizes, int n_in,
                              void* d_out, int out_size, void* d_ws, size_t ws_size,
                              hipStream_t stream) {
    const float* entity_emb   = (const float*)d_in[0];
    const float* relation_emb = (const float*)d_in[1];
    const float* a_heads      = (const float*)d_in[2]; // 2 x 200 x 600
    const float* a2_heads     = (const float*)d_in[3]; // 2 x 1 x 200
    const float* W_rel        = (const float*)d_in[4]; // 200 x 400
    const float* a_out        = (const float*)d_in[5]; // 400 x 1200
    const float* a2_out       = (const float*)d_in[6]; // 1 x 400
    const float* W_entities   = (const float*)d_in[7]; // 200 x 400
    const int* el  = (const int*)d_in[8];   // 2 x 250000
    const int* et  = (const int*)d_in[9];   // 250000
    const int* tin = (const int*)d_in[10];  // 50000 x 4
    const int* batch = (const int*)d_in[11];// 8192 x 3

    float* out = (float*)d_out; // [0,12M): out_ent ; [12M,12.2M): out_rel

    // -------- workspace arena (floats) --------
    float* w = (float*)d_ws;
    size_t off = 0;
    auto alloc = [&](size_t n) { float* p = w + off; off += n; return p; };
    float* ent_n   = alloc(6000000);   // 30000 x 200
    float* rel_n   = alloc(100000);    // 500 x 200
    float* out_ent = alloc(12000000);  // 30000 x 400 (layer-1 output / layer-2 input)
    float* Ui      = alloc(12000000);  // layer1: Qi = Ui, Qj = Ui + 6M ; layer2: U_i
    float* Uj      = alloc(12000000);  // layer2 U_j, later Z = ent_n @ W_entities
    float* Ur      = alloc(12000000);  // layer2 U_r
    float* Rr      = alloc(200000);    // layer1 R_r (500x200) / layer2 V_r (500x400)
    float* Wi      = alloc(40000);     // combined a_i + a_r
    float* Wj      = alloc(40000);     // combined a_j + a_r
    float* s_i     = alloc(30000);     // / t_i
    float* s_j     = alloc(30000);     // / t_j
    float* t_r     = alloc(30000);
    float* s_r     = alloc(500);       // / t_v
    float* edge_e  = alloc(300000);
    float* rowsum0 = alloc(30000);
    float* rowsum1 = alloc(30000);
    float* rowsum2 = alloc(30000);
    float* rowsumNH= alloc(30000);
    float* maskv   = alloc(30000);
    float* tmp_rel = alloc(200000);    // out_rel (rel@W_rel), later rel@W_entities
    (void)ws_size; (void)in_sizes; (void)n_in; (void)out_size;

    // -------- zero what is accumulated into --------
    hipMemsetAsync(out_ent, 0, 12000000ull * 4, stream);
    hipMemsetAsync(rowsum0, 0, (30000ull * 5) * 4, stream); // rowsum0,1,2,NH,maskv contiguous
    hipMemsetAsync(out, 0, 12000000ull * 4, stream);        // h2 accumulator region

    // -------- normalize inputs --------
    l2norm_rows<<<N_ENT_C, 64, 0, stream>>>(entity_emb, ent_n, D_IN_C);
    l2norm_rows<<<N_REL_C, 64, 0, stream>>>(relation_emb, rel_n, D_IN_C);

    // -------- layer 1, per head --------
    float* rowsums[2] = {rowsum0, rowsum1};
    for (int h = 0; h < 2; ++h) {
        const float* Ah  = a_heads + (size_t)h * 200 * 600;
        const float* a2h = a2_heads + (size_t)h * 200;
        float* Qi = Ui;
        float* Qj = Ui + 6000000;

        combine_w<<<ceil_div(40000, 256), 256, 0, stream>>>(Ah, Wi, Wj);
        {
            dim3 g(ceil_div(D_IN_C, 64), ceil_div(N_ENT_C, 64));
            gemm_kernel<true><<<g, 256, 0, stream>>>(ent_n, D_IN_C, Wi, nullptr, D_IN_C,
                                                     Qi, D_IN_C, N_ENT_C, D_IN_C, D_IN_C);
            gemm_kernel<true><<<g, 256, 0, stream>>>(ent_n, D_IN_C, Wj, nullptr, D_IN_C,
                                                     Qj, D_IN_C, N_ENT_C, D_IN_C, D_IN_C);
        }
        {
            dim3 g(ceil_div(D_IN_C, 64), ceil_div(N_REL_C, 64));
            gemm_kernel<true><<<g, 256, 0, stream>>>(rel_n, D_IN_C, Ah + 400, nullptr, 600,
                                                     Rr, D_IN_C, N_REL_C, D_IN_C, D_IN_C);
        }
        rowdot<<<N_ENT_C, 64, 0, stream>>>(Qi, D_IN_C, a2h, s_i, D_IN_C);
        rowdot<<<N_ENT_C, 64, 0, stream>>>(Qj, D_IN_C, a2h, s_j, D_IN_C);
        rowdot<<<N_REL_C, 64, 0, stream>>>(Rr, D_IN_C, a2h, s_r, D_IN_C);

        edge_scalar1<<<ceil_div(E_TOT_C, 256), 256, 0, stream>>>(el, et, tin, s_i, s_j, s_r,
                                                                 edge_e, rowsums[h]);
        scatter1<<<ceil_div(E_TOT_C * 64, 256), 256, 0, stream>>>(el, et, tin, edge_e, Qj, Rr,
                                                                  out_ent, h * 200);
        fin1<<<N_ENT_C, 64, 0, stream>>>(out_ent, Qi, rowsums[h], h * 200);
    }

    // -------- out_rel = rel_n @ W_rel (500 x 400) --------
    {
        dim3 g(ceil_div(D_HID_C, 64), ceil_div(N_REL_C, 64));
        gemm_kernel<false><<<g, 256, 0, stream>>>(rel_n, D_IN_C, W_rel, nullptr, D_HID_C,
                                                  tmp_rel, D_HID_C, N_REL_C, D_HID_C, D_IN_C);
    }

    // -------- layer-2 projections --------
    {
        dim3 g(ceil_div(D_HID_C, 64), ceil_div(N_ENT_C, 64));
        gemm_kernel<true><<<g, 256, 0, stream>>>(out_ent, D_HID_C, a_out + 0, nullptr, 1200,
                                                 Ui, D_HID_C, N_ENT_C, D_HID_C, D_HID_C);
        gemm_kernel<true><<<g, 256, 0, stream>>>(out_ent, D_HID_C, a_out + 400, nullptr, 1200,
                                                 Uj, D_HID_C, N_ENT_C, D_HID_C, D_HID_C);
        gemm_kernel<true><<<g, 256, 0, stream>>>(out_ent, D_HID_C, a_out + 800, nullptr, 1200,
                                                 Ur, D_HID_C, N_ENT_C, D_HID_C, D_HID_C);
    }
    {
        dim3 g(ceil_div(D_HID_C, 64), ceil_div(N_REL_C, 64));
        gemm_kernel<true><<<g, 256, 0, stream>>>(tmp_rel, D_HID_C, a_out + 800, nullptr, 1200,
                                                 Rr, D_HID_C, N_REL_C, D_HID_C, D_HID_C);
    }
    rowdot<<<N_ENT_C, 64, 0, stream>>>(Ui, D_HID_C, a2_out, s_i, D_HID_C);
    rowdot<<<N_ENT_C, 64, 0, stream>>>(Uj, D_HID_C, a2_out, s_j, D_HID_C);
    rowdot<<<N_ENT_C, 64, 0, stream>>>(Ur, D_HID_C, a2_out, t_r, D_HID_C);
    rowdot<<<N_REL_C, 64, 0, stream>>>(Rr, D_HID_C, a2_out, s_r, D_HID_C);

    edge_scalar2<<<ceil_div(E_TOT_C, 256), 256, 0, stream>>>(el, et, tin, s_i, s_j, t_r, s_r,
                                                             edge_e, rowsum2, rowsumNH);
    scatter2<<<ceil_div(E_TOT_C * 64, 256), 256, 0, stream>>>(el, et, tin, edge_e, Uj, Ur, Rr,
                                                              out);

    // -------- Z = ent_n @ W_entities (reuse Uj; it is dead after scatter2) --------
    {
        dim3 g(ceil_div(D_HID_C, 64), ceil_div(N_ENT_C, 64));
        gemm_kernel<false><<<g, 256, 0, stream>>>(ent_n, D_IN_C, W_entities, nullptr, D_HID_C,
                                                  Uj, D_HID_C, N_ENT_C, D_HID_C, D_IN_C);
    }
    // rel_n @ W_entities -> tmp_rel (out_rel intermediate dead after V_r GEMM)
    {
        dim3 g(ceil_div(D_HID_C, 64), ceil_div(N_REL_C, 64));
        gemm_kernel<false><<<g, 256, 0, stream>>>(rel_n, D_IN_C, W_entities, nullptr, D_HID_C,
                                                  tmp_rel, D_HID_C, N_REL_C, D_HID_C, D_IN_C);
    }

    mask_scatter<<<ceil_div(NB_C, 256), 256, 0, stream>>>(batch, maskv);

    fin2<<<N_ENT_C, 64, 0, stream>>>(out, Ui, Ur, rowsum2, rowsumNH, Uj, maskv);
    l2norm_rows<<<N_REL_C, 64, 0, stream>>>(tmp_rel, out + 12000000, D_HID_C);
}

// Round 5
// 1609.761 us; speedup vs baseline: 1.7853x; 1.7853x over previous
//
#include <hip/hip_runtime.h>
#include <hip/hip_bf16.h>
#include <math.h>

// ---------------- problem constants (from reference) ----------------
constexpr int N_ENT_C = 30000;
constexpr int N_REL_C = 500;
constexpr int D_IN_C  = 200;
constexpr int D_HID_C = 400;     // NHEADS * D_OUT1
constexpr int E1_C    = 250000;
constexpr int E2_C    = 50000;
constexpr int E_TOT_C = 300000;
constexpr int NB_C    = 8192;

static inline int ceil_div(int a, int b) { return (a + b - 1) / b; }

// ---------------- row-wise L2 normalize
__global__ void l2norm_rows(const float* __restrict__ in, float* __restrict__ out, int D) {
    int n = blockIdx.x;
    int lane = threadIdx.x; // 64
    const float* src = in + (size_t)n * D;
    float vals[7];
    float ss = 0.f;
#pragma unroll
    for (int i = 0; i < 7; ++i) {
        int o = lane + i * 64;
        float v = (o < D) ? src[o] : 0.f;
        vals[i] = v;
        ss += v * v;
    }
#pragma unroll
    for (int off = 32; off; off >>= 1) ss += __shfl_down(ss, off);
    ss = __shfl(ss, 0);
    float inv = 1.f / fmaxf(sqrtf(ss), 1e-12f);
    float* dst = out + (size_t)n * D;
#pragma unroll
    for (int i = 0; i < 7; ++i) {
        int o = lane + i * 64;
        if (o < D) dst[o] = vals[i] * inv;
    }
}

// ---------------- Wcat[800][200]: rows = [Wi0, Wj0, Wi1, Wj1], W*_h = a_*_h + a_r_h
__global__ void combine_w(const float* __restrict__ A /* [2][200][600] */, float* __restrict__ Wcat) {
    int i = blockIdx.x * 256 + threadIdx.x;
    if (i >= 800 * 200) return;
    int r = i / 200, d = i % 200;
    int h = r / 400;
    int rr = r % 400;
    int isj = rr / 200;      // 0: Wi, 1: Wj
    int o = rr % 200;
    const float* Ah = A + (size_t)h * 200 * 600;
    Wcat[i] = Ah[o * 600 + isj * 200 + d] + Ah[o * 600 + 400 + d];
}

// ---------------- W2[1200][400]: packed a_out^T slices; W2[n][k] = a_out[n%400][ (n/400)*400 + k ]
__global__ void pack_aout(const float* __restrict__ a_out /* [400][1200] */, float* __restrict__ W2) {
    int i = blockIdx.x * 256 + threadIdx.x;
    if (i >= 1200 * 400) return;
    int n = i / 400, k = i % 400;
    int seg = n / 400;   // 0: a_i, 1: a_j, 2: a_r
    int o = n % 400;
    W2[i] = a_out[(size_t)o * 1200 + seg * 400 + k];
}

// ---------------- CSR build ----------------
__global__ void csr_count(const int* __restrict__ el, const int* __restrict__ tin,
                          int* __restrict__ deg) {
    int k = blockIdx.x * 256 + threadIdx.x;
    if (k >= E_TOT_C) return;
    int e0 = (k < E1_C) ? el[k] : tin[4 * (k - E1_C) + 3];
    atomicAdd(&deg[e0], 1);
}

__global__ __launch_bounds__(1024) void scan_offsets(const int* __restrict__ deg,
                                                     int* __restrict__ off,
                                                     int* __restrict__ cursor, int n) {
    __shared__ int tmp[1024];
    __shared__ int carry;
    int tid = threadIdx.x;
    if (tid == 0) carry = 0;
    __syncthreads();
    for (int base = 0; base < n; base += 1024) {
        int i = base + tid;
        int v = (i < n) ? deg[i] : 0;
        tmp[tid] = v;
        __syncthreads();
        for (int s = 1; s < 1024; s <<= 1) {
            int t = (tid >= s) ? tmp[tid - s] : 0;
            __syncthreads();
            tmp[tid] += t;
            __syncthreads();
        }
        int ex = carry + tmp[tid] - v; // exclusive
        if (i < n) { off[i] = ex; cursor[i] = ex; }
        __syncthreads();
        if (tid == 1023) carry += tmp[1023];
        __syncthreads();
    }
    if (tid == 0) off[n] = carry;
}

__global__ void csr_place(const int* __restrict__ el, const int* __restrict__ tin,
                          int* __restrict__ cursor, int* __restrict__ eidx) {
    int k = blockIdx.x * 256 + threadIdx.x;
    if (k >= E_TOT_C) return;
    int e0 = (k < E1_C) ? el[k] : tin[4 * (k - E1_C) + 3];
    int p = atomicAdd(&cursor[e0], 1);
    eidx[p] = k;
}

// ---------------- 128x128 tiled f32 GEMM, 8x8 acc/thread ----------------
// NT: W[n*ldw + k];  NN: W[k*ldw + n]
template <bool NT>
__global__ __launch_bounds__(256) void gemm128(
    const float* __restrict__ X, int ldx,
    const float* __restrict__ W, int ldw,
    float* __restrict__ C, int ldc, int M, int N, int K)
{
    __shared__ float Xs[16][132];
    __shared__ float Ws[16][132];
    const int bm = blockIdx.y * 128;
    const int bn = blockIdx.x * 128;
    const int tid = threadIdx.x;
    const int tm = (tid >> 4) * 4;  // 0..60
    const int tn = (tid & 15) * 4;  // 0..60
    float acc[8][8] = {};
    for (int k0 = 0; k0 < K; k0 += 16) {
        // X tile (row-major [m][k]) -> Xs[k][m], float4 over k
        for (int i = tid; i < 512; i += 256) {
            int mm = i >> 2, k4 = (i & 3) << 2;
            int m = bm + mm, k = k0 + k4;
            float4 xv = {0.f, 0.f, 0.f, 0.f};
            if (m < M) {
                if (k + 3 < K) xv = *(const float4*)&X[(size_t)m * ldx + k];
                else {
                    float t0 = (k < K) ? X[(size_t)m * ldx + k] : 0.f;
                    float t1 = (k + 1 < K) ? X[(size_t)m * ldx + k + 1] : 0.f;
                    float t2 = (k + 2 < K) ? X[(size_t)m * ldx + k + 2] : 0.f;
                    float t3 = (k + 3 < K) ? X[(size_t)m * ldx + k + 3] : 0.f;
                    xv = make_float4(t0, t1, t2, t3);
                }
            }
            Xs[k4 + 0][mm] = xv.x; Xs[k4 + 1][mm] = xv.y;
            Xs[k4 + 2][mm] = xv.z; Xs[k4 + 3][mm] = xv.w;
        }
        if (NT) {
            for (int i = tid; i < 512; i += 256) {
                int nn = i >> 2, k4 = (i & 3) << 2;
                int n = bn + nn, k = k0 + k4;
                float4 wv = {0.f, 0.f, 0.f, 0.f};
                if (n < N) {
                    if (k + 3 < K) wv = *(const float4*)&W[(size_t)n * ldw + k];
                    else {
                        float t0 = (k < K) ? W[(size_t)n * ldw + k] : 0.f;
                        float t1 = (k + 1 < K) ? W[(size_t)n * ldw + k + 1] : 0.f;
                        float t2 = (k + 2 < K) ? W[(size_t)n * ldw + k + 2] : 0.f;
                        float t3 = (k + 3 < K) ? W[(size_t)n * ldw + k + 3] : 0.f;
                        wv = make_float4(t0, t1, t2, t3);
                    }
                }
                Ws[k4 + 0][nn] = wv.x; Ws[k4 + 1][nn] = wv.y;
                Ws[k4 + 2][nn] = wv.z; Ws[k4 + 3][nn] = wv.w;
            }
        } else {
            for (int i = tid; i < 512; i += 256) {
                int kk = i >> 5, nn4 = (i & 31) << 2;
                int n = bn + nn4, k = k0 + kk;
                float4 wv = {0.f, 0.f, 0.f, 0.f};
                if (k < K) {
                    if (n + 3 < N) wv = *(const float4*)&W[(size_t)k * ldw + n];
                    else {
                        float t0 = (n < N) ? W[(size_t)k * ldw + n] : 0.f;
                        float t1 = (n + 1 < N) ? W[(size_t)k * ldw + n + 1] : 0.f;
                        float t2 = (n + 2 < N) ? W[(size_t)k * ldw + n + 2] : 0.f;
                        float t3 = (n + 3 < N) ? W[(size_t)k * ldw + n + 3] : 0.f;
                        wv = make_float4(t0, t1, t2, t3);
                    }
                }
                *(float4*)&Ws[kk][nn4] = wv;
            }
        }
        __syncthreads();
#pragma unroll
        for (int kk = 0; kk < 16; ++kk) {
            float xv[8], wv[8];
            *(float4*)&xv[0] = *(const float4*)&Xs[kk][tm];
            *(float4*)&xv[4] = *(const float4*)&Xs[kk][tm + 64];
            *(float4*)&wv[0] = *(const float4*)&Ws[kk][tn];
            *(float4*)&wv[4] = *(const float4*)&Ws[kk][tn + 64];
#pragma unroll
            for (int a = 0; a < 8; ++a)
#pragma unroll
                for (int b = 0; b < 8; ++b) acc[a][b] += xv[a] * wv[b];
        }
        __syncthreads();
    }
#pragma unroll
    for (int a = 0; a < 8; ++a) {
        int m = bm + tm + (a & 3) + (a >> 2) * 64;
        if (m >= M) continue;
#pragma unroll
        for (int b = 0; b < 8; ++b) {
            int n = bn + tn + (b & 3) + (b >> 2) * 64;
            if (n < N) C[(size_t)m * ldc + n] = acc[a][b];
        }
    }
}

// ---------------- 64x64 tiled f32 GEMM (small matrices) ----------------
template <bool NT>
__global__ __launch_bounds__(256) void gemm64(
    const float* __restrict__ X, int ldx,
    const float* __restrict__ W, int ldw,
    float* __restrict__ C, int ldc, int M, int N, int K)
{
    __shared__ float Xs[16][65];
    __shared__ float Ws[16][65];
    const int bm = blockIdx.y * 64;
    const int bn = blockIdx.x * 64;
    const int tid = threadIdx.x;
    const int tm = (tid >> 4) << 2;
    const int tn = (tid & 15) << 2;
    float acc[4][4] = {};
    for (int k0 = 0; k0 < K; k0 += 16) {
        for (int i = tid; i < 64 * 16; i += 256) {
            int mm = i >> 4, kk = i & 15;
            int m = bm + mm, k = k0 + kk;
            Xs[kk][mm] = (m < M && k < K) ? X[(size_t)m * ldx + k] : 0.f;
        }
        for (int i = tid; i < 64 * 16; i += 256) {
            int nn = i >> 4, kk = i & 15;
            int n = bn + nn, k = k0 + kk;
            float w = 0.f;
            if (n < N && k < K) w = NT ? W[(size_t)n * ldw + k] : W[(size_t)k * ldw + n];
            Ws[kk][nn] = w;
        }
        __syncthreads();
#pragma unroll
        for (int kk = 0; kk < 16; ++kk) {
            float xv[4], wv[4];
#pragma unroll
            for (int a = 0; a < 4; ++a) xv[a] = Xs[kk][tm + a];
#pragma unroll
            for (int b = 0; b < 4; ++b) wv[b] = Ws[kk][tn + b];
#pragma unroll
            for (int a = 0; a < 4; ++a)
#pragma unroll
                for (int b = 0; b < 4; ++b) acc[a][b] += xv[a] * wv[b];
        }
        __syncthreads();
    }
#pragma unroll
    for (int a = 0; a < 4; ++a) {
        int m = bm + tm + a;
        if (m >= M) continue;
#pragma unroll
        for (int b = 0; b < 4; ++b) {
            int n = bn + tn + b;
            if (n < N) C[(size_t)m * ldc + n] = acc[a][b];
        }
    }
}

// ---------------- out[m] = sum_o A[m*lda+o] * v[o] (small) ----------------
__global__ void rowdot(const float* __restrict__ A, int lda, const float* __restrict__ v,
                       float* __restrict__ out, int D) {
    int m = blockIdx.x;
    int lane = threadIdx.x; // 64
    const float* row = A + (size_t)m * lda;
    float s = 0.f;
    for (int o = lane; o < D; o += 64) s += row[o] * v[o];
#pragma unroll
    for (int off = 32; off; off >>= 1) s += __shfl_down(s, off);
    if (lane == 0) out[m] = s;
}

// ---------------- s4[n][4] = {Qi0.a20, Qj0.a20, Qi1.a21, Qj1.a21} ----------------
__global__ __launch_bounds__(256) void rowdot4h(const float* __restrict__ Q,
                                                const float* __restrict__ a2h,
                                                float* __restrict__ s4) {
    int n = blockIdx.x * 4 + (threadIdx.x >> 6);
    if (n >= N_ENT_C) return;
    int lane = threadIdx.x & 63;
    const float* row = Q + (size_t)n * 800;
#pragma unroll
    for (int seg = 0; seg < 4; ++seg) {
        const float* v = a2h + (seg >> 1) * 200;
        float s = 0.f;
        for (int o = lane; o < 200; o += 64) s += row[seg * 200 + o] * v[o];
#pragma unroll
        for (int off = 32; off; off >>= 1) s += __shfl_down(s, off);
        if (lane == 0) s4[n * 4 + seg] = s;
    }
}

// ---------------- s3[n][3] = {Ui.a2o, Uj.a2o, Ur.a2o} over U[n][1200] ----------------
__global__ __launch_bounds__(256) void rowdot3(const float* __restrict__ U,
                                               const float* __restrict__ a2o,
                                               float* __restrict__ s3) {
    int n = blockIdx.x * 4 + (threadIdx.x >> 6);
    if (n >= N_ENT_C) return;
    int lane = threadIdx.x & 63;
    const float* row = U + (size_t)n * 1200;
#pragma unroll
    for (int seg = 0; seg < 3; ++seg) {
        float s = 0.f;
        for (int o = lane; o < 400; o += 64) s += row[seg * 400 + o] * a2o[o];
#pragma unroll
        for (int off = 32; off; off >>= 1) s += __shfl_down(s, off);
        if (lane == 0) s3[n * 3 + seg] = s;
    }
}

// ---------------- layer-1 aggregation (both heads), fused finalize ----------------
__global__ __launch_bounds__(256) void agg1(
    const int* __restrict__ off, const int* __restrict__ eidx,
    const int* __restrict__ el, const int* __restrict__ et, const int* __restrict__ tin,
    const float* __restrict__ Q /* [N][800] */, const float* __restrict__ Rr /* [2][500*200] */,
    const float* __restrict__ s4, const float* __restrict__ sr /* [2][500] */,
    float* __restrict__ out_ent /* [N][400] */)
{
    int n = blockIdx.x * 4 + (threadIdx.x >> 6);
    if (n >= N_ENT_C) return;
    int lane = threadIdx.x & 63;
    float acc0[4] = {}, acc1[4] = {};
    float rs0 = 0.f, rs1 = 0.f;
    float si0 = s4[n * 4 + 0], si1 = s4[n * 4 + 2];
    int jb = off[n], je = off[n + 1];
    for (int j = jb; j < je; ++j) {
        int k = eidx[j];
        int e1;
        float d0, d1;
        const float* ra0; const float* ra1;
        const float* rb0 = nullptr; const float* rb1 = nullptr;
        if (k < E1_C) {
            e1 = el[E1_C + k];
            int t = et[k];
            d0 = si0 + s4[e1 * 4 + 1] + sr[t];
            d1 = si1 + s4[e1 * 4 + 3] + sr[500 + t];
            ra0 = Rr + (size_t)t * 200;
            ra1 = Rr + 100000 + (size_t)t * 200;
        } else {
            const int4 t = ((const int4*)tin)[k - E1_C];
            e1 = t.x;
            d0 = si0 + s4[e1 * 4 + 1] + sr[t.y] + sr[t.z];
            d1 = si1 + s4[e1 * 4 + 3] + sr[500 + t.y] + sr[500 + t.z];
            ra0 = Rr + (size_t)t.y * 200; rb0 = Rr + (size_t)t.z * 200;
            ra1 = Rr + 100000 + (size_t)t.y * 200; rb1 = Rr + 100000 + (size_t)t.z * 200;
        }
        d0 = (d0 > 0.f) ? d0 : 0.2f * d0;
        d1 = (d1 > 0.f) ? d1 : 0.2f * d1;
        float e0 = expf(-d0), e1f = expf(-d1);
        rs0 += e0; rs1 += e1f;
        const float* qj = Q + (size_t)e1 * 800;
#pragma unroll
        for (int i = 0; i < 4; ++i) {
            int o = lane + i * 64;
            if (o < 200) {
                float p0 = qj[200 + o] + ra0[o];
                float p1 = qj[600 + o] + ra1[o];
                if (rb0) { p0 += rb0[o]; p1 += rb1[o]; }
                acc0[i] += e0 * p0;
                acc1[i] += e1f * p1;
            }
        }
    }
    const float* qi = Q + (size_t)n * 800;
    float* dst = out_ent + (size_t)n * 400;
#pragma unroll
    for (int i = 0; i < 4; ++i) {
        int o = lane + i * 64;
        if (o < 200) {
            float v0 = (rs0 > 0.f) ? (qi[o] + acc0[i] / rs0) : 0.f;
            float v1 = (rs1 > 0.f) ? (qi[400 + o] + acc1[i] / rs1) : 0.f;
            dst[o]       = (v0 > 0.f) ? v0 : (expf(v0) - 1.f);
            dst[200 + o] = (v1 > 0.f) ? v1 : (expf(v1) - 1.f);
        }
    }
}

// ---------------- layer-2 aggregation, fused finalize + mask + Z + l2norm ----------------
__global__ __launch_bounds__(256) void agg2(
    const int* __restrict__ off, const int* __restrict__ eidx,
    const int* __restrict__ el, const int* __restrict__ et, const int* __restrict__ tin,
    const float* __restrict__ U /* [N][1200] */, const float* __restrict__ Vr /* [500][400] */,
    const float* __restrict__ s3, const float* __restrict__ sv /* [500] */,
    const float* __restrict__ Z /* [N][400] */, const float* __restrict__ mask,
    float* __restrict__ outp /* [N][400] */)
{
    int n = blockIdx.x * 4 + (threadIdx.x >> 6);
    if (n >= N_ENT_C) return;
    int lane = threadIdx.x & 63;
    float acc[7] = {};
    float rs = 0.f, rsnh = 0.f;
    float ti = s3[n * 3 + 0], trn = s3[n * 3 + 2];
    int jb = off[n], je = off[n + 1];
    for (int j = jb; j < je; ++j) {
        int k = eidx[j];
        int e1;
        float dot;
        bool nh = (k >= E1_C);
        const float* v0; const float* v1 = nullptr;
        if (!nh) {
            e1 = el[E1_C + k];
            int t = et[k];
            dot = ti + s3[e1 * 3 + 1] + sv[t];
            v0 = Vr + (size_t)t * 400;
        } else {
            const int4 t = ((const int4*)tin)[k - E1_C];
            e1 = t.x;
            dot = ti + trn + s3[e1 * 3 + 1] + s3[e1 * 3 + 2] + sv[t.y] + sv[t.z];
            v0 = Vr + (size_t)t.y * 400;
            v1 = Vr + (size_t)t.z * 400;
        }
        float p = (dot > 0.f) ? dot : 0.2f * dot;
        float e = expf(-p);
        rs += e;
        if (nh) rsnh += e;
        const float* ue = U + (size_t)e1 * 1200;
#pragma unroll
        for (int i = 0; i < 7; ++i) {
            int o = lane + i * 64;
            if (o < 400) {
                float v = ue[400 + o] + v0[o];
                if (nh) v += ue[800 + o] + v1[o];
                acc[i] += e * v;
            }
        }
    }
    const float* un = U + (size_t)n * 1200;
    const float* z = Z + (size_t)n * 400;
    float mk = mask[n];
    float vals[7];
    float ss = 0.f;
#pragma unroll
    for (int i = 0; i < 7; ++i) {
        int o = lane + i * 64;
        float v = 0.f;
        if (o < 400) {
            float hv = (rs > 0.f) ? (un[o] + (acc[i] + un[800 + o] * rsnh) / rs) : 0.f;
            float oe = (hv > 0.f) ? hv : (expf(hv) - 1.f);
            v = z[o] + mk * oe;
        }
        vals[i] = v;
        ss += v * v;
    }
#pragma unroll
    for (int offs = 32; offs; offs >>= 1) ss += __shfl_down(ss, offs);
    ss = __shfl(ss, 0);
    float inv = 1.f / fmaxf(sqrtf(ss), 1e-12f);
    float* row = outp + (size_t)n * 400;
#pragma unroll
    for (int i = 0; i < 7; ++i) {
        int o = lane + i * 64;
        if (o < 400) row[o] = vals[i] * inv;
    }
}

// ---------------- mask scatter ----------------
__global__ void mask_scatter(const int* __restrict__ batch, float* __restrict__ mask) {
    int t = blockIdx.x * 256 + threadIdx.x;
    if (t >= NB_C) return;
    mask[batch[t * 3 + 2]] = 1.0f;
}

// =====================================================================
extern "C" void kernel_launch(void* const* d_in, const int* in_sizes, int n_in,
                              void* d_out, int out_size, void* d_ws, size_t ws_size,
                              hipStream_t stream) {
    const float* entity_emb   = (const float*)d_in[0];
    const float* relation_emb = (const float*)d_in[1];
    const float* a_heads      = (const float*)d_in[2]; // 2 x 200 x 600
    const float* a2_heads     = (const float*)d_in[3]; // 2 x 1 x 200
    const float* W_rel        = (const float*)d_in[4]; // 200 x 400
    const float* a_out        = (const float*)d_in[5]; // 400 x 1200
    const float* a2_out       = (const float*)d_in[6]; // 1 x 400
    const float* W_entities   = (const float*)d_in[7]; // 200 x 400
    const int* el  = (const int*)d_in[8];   // 2 x 250000
    const int* et  = (const int*)d_in[9];   // 250000
    const int* tin = (const int*)d_in[10];  // 50000 x 4
    const int* batch = (const int*)d_in[11];// 8192 x 3

    float* out = (float*)d_out; // [0,12M): out_ent ; [12M,12.2M): out_rel

    // -------- workspace arena --------
    float* w = (float*)d_ws;
    size_t off_f = 0;
    auto alloc = [&](size_t n) { float* p = w + off_f; off_f += n; return p; };
    float* ent_n   = alloc(6000000);   // 30000 x 200
    float* rel_n   = alloc(100000);    // 500 x 200
    float* out_ent = alloc(12000000);  // layer-1 out [30000][400]; reused for Z
    float* U       = alloc(36000000);  // layer1: Q=[30000][800] (first 24M); layer2: U=[30000][1200]
    float* Vrbuf   = alloc(200000);    // layer1 Rr [2][500*200] / layer2 Vr [500][400]
    float* Wcat    = alloc(160000);    // [800][200]
    float* W2      = alloc(480000);    // packed a_out -> [1200][400]
    float* s4      = alloc(120000);    // [30000][4]; also s3 [30000][3]
    float* srb     = alloc(1000);      // [2][500]; also sv [500]
    float* tmp_rel = alloc(200000);    // out_rel [500][400]; later rel@W_entities
    float* maskv   = alloc(30000);
    int* deg    = (int*)(w + off_f); off_f += 30000;
    int* offs   = (int*)(w + off_f); off_f += 30008;
    int* cursor = (int*)(w + off_f); off_f += 30000;
    int* eidx   = (int*)(w + off_f); off_f += 300000;
    (void)ws_size; (void)in_sizes; (void)n_in; (void)out_size;

    float* Q = U; // layer-1 alias

    // -------- zero mask + degree (adjacent in arena) --------
    hipMemsetAsync(maskv, 0, (30000ull + 30000ull) * 4, stream);

    // -------- normalize inputs --------
    l2norm_rows<<<N_ENT_C, 64, 0, stream>>>(entity_emb, ent_n, D_IN_C);
    l2norm_rows<<<N_REL_C, 64, 0, stream>>>(relation_emb, rel_n, D_IN_C);

    // -------- CSR build (shared by both layers) --------
    csr_count<<<ceil_div(E_TOT_C, 256), 256, 0, stream>>>(el, tin, deg);
    scan_offsets<<<1, 1024, 0, stream>>>(deg, offs, cursor, N_ENT_C);
    csr_place<<<ceil_div(E_TOT_C, 256), 256, 0, stream>>>(el, tin, cursor, eidx);

    // -------- layer-1 projections (fused: both heads, i+j) --------
    combine_w<<<ceil_div(160000, 256), 256, 0, stream>>>(a_heads, Wcat);
    {
        dim3 g(ceil_div(800, 128), ceil_div(N_ENT_C, 128));
        gemm128<true><<<g, 256, 0, stream>>>(ent_n, 200, Wcat, 200, Q, 800,
                                             N_ENT_C, 800, 200);
    }
    for (int h = 0; h < 2; ++h) {
        dim3 g(ceil_div(200, 64), ceil_div(N_REL_C, 64));
        gemm64<true><<<g, 256, 0, stream>>>(rel_n, 200, a_heads + (size_t)h * 120000 + 400, 600,
                                            Vrbuf + (size_t)h * 100000, 200, N_REL_C, 200, 200);
    }
    rowdot4h<<<ceil_div(N_ENT_C, 4), 256, 0, stream>>>(Q, a2_heads, s4);
    rowdot<<<N_REL_C, 64, 0, stream>>>(Vrbuf, 200, a2_heads, srb, 200);
    rowdot<<<N_REL_C, 64, 0, stream>>>(Vrbuf + 100000, 200, a2_heads + 200, srb + 500, 200);

    agg1<<<ceil_div(N_ENT_C, 4), 256, 0, stream>>>(offs, eidx, el, et, tin, Q, Vrbuf, s4, srb,
                                                   out_ent);

    // -------- out_rel = rel_n @ W_rel --------
    {
        dim3 g(ceil_div(400, 64), ceil_div(N_REL_C, 64));
        gemm64<false><<<g, 256, 0, stream>>>(rel_n, 200, W_rel, 400, tmp_rel, 400,
                                             N_REL_C, 400, 200);
    }

    // -------- layer-2 projections: U = out_ent @ [a_i|a_j|a_r]^T via packed W2 --------
    pack_aout<<<ceil_div(480000, 256), 256, 0, stream>>>(a_out, W2);
    {
        dim3 g(ceil_div(1200, 128), ceil_div(N_ENT_C, 128));
        gemm128<true><<<g, 256, 0, stream>>>(out_ent, 400, W2, 400, U, 1200,
                                             N_ENT_C, 1200, 400);
    }
    {
        dim3 g(ceil_div(400, 64), ceil_div(N_REL_C, 64));
        gemm64<true><<<g, 256, 0, stream>>>(tmp_rel, 400, a_out + 800, 1200, Vrbuf, 400,
                                            N_REL_C, 400, 400);
    }
    rowdot3<<<ceil_div(N_ENT_C, 4), 256, 0, stream>>>(U, a2_out, s4);
    rowdot<<<N_REL_C, 64, 0, stream>>>(Vrbuf, 400, a2_out, srb, 400);

    // -------- Z = ent_n @ W_entities -> reuse out_ent (dead after U GEMM) --------
    {
        dim3 g(ceil_div(400, 128), ceil_div(N_ENT_C, 128));
        gemm128<false><<<g, 256, 0, stream>>>(ent_n, 200, W_entities, 400, out_ent, 400,
                                              N_ENT_C, 400, 200);
    }
    // rel @ W_entities -> tmp_rel (dead after Vr GEMM)
    {
        dim3 g(ceil_div(400, 64), ceil_div(N_REL_C, 64));
        gemm64<false><<<g, 256, 0, stream>>>(rel_n, 200, W_entities, 400, tmp_rel, 400,
                                             N_REL_C, 400, 200);
    }

    mask_scatter<<<ceil_div(NB_C, 256), 256, 0, stream>>>(batch, maskv);

    agg2<<<ceil_div(N_ENT_C, 4), 256, 0, stream>>>(offs, eidx, el, et, tin, U, Vrbuf, s4, srb,
                                                   out_ent, maskv, out);
    l2norm_rows<<<N_REL_C, 64, 0, stream>>>(tmp_rel, out + 12000000, D_HID_C);
}